// Round 7
// baseline (831.117 us; speedup 1.0000x reference)
//
#include <hip/hip_runtime.h>

constexpr int N_NODES = 100000;
constexpr int F1 = 64;   // IN_DIM == HID_DIM
constexpr int F2 = 16;   // OUT_DIM
constexpr int SH = 6;                             // bin = dst >> 6
constexpr int NPB = 64;                           // nodes per bin
constexpr int NBINS = (N_NODES + NPB - 1) / NPB;  // 1563
constexpr int CAPB = 1344;                        // mean 1024, +10 sigma
constexpr int TILE = 4096;                        // edges per k_bin block
constexpr int GSTRIDE = 16;                       // gcnt: one counter per 64B line

// bf16 helpers (RNE)
static __device__ __forceinline__ unsigned short f2bf(float f) {
    unsigned int u = __float_as_uint(f);
    unsigned int r = (u + 0x7fffu + ((u >> 16) & 1u)) >> 16;
    return (unsigned short)r;
}
static __device__ __forceinline__ float bf2f(unsigned short b) {
    return __uint_as_float(((unsigned int)b) << 16);
}

// ---------------- pass 1: coarse binning (block-aggregated allocation) ----------------
__global__ __launch_bounds__(256) void k_bin(const int* __restrict__ src,
                                             const int* __restrict__ dst, int E,
                                             unsigned int* __restrict__ gcnt,
                                             unsigned int* __restrict__ entries) {
    __shared__ unsigned int cnt[NBINS];
    __shared__ unsigned int cur[NBINS];
    int tid = threadIdx.x;
    int base = blockIdx.x * TILE;
    int end = min(base + TILE, E);
    for (int i = tid; i < NBINS; i += 256) cnt[i] = 0;
    __syncthreads();
    for (int e = base + tid; e < end; e += 256) atomicAdd(&cnt[dst[e] >> SH], 1u);
    __syncthreads();
    for (int i = tid; i < NBINS; i += 256) {
        unsigned int c = cnt[i];
        cur[i] = (unsigned int)i * CAPB + (c ? atomicAdd(&gcnt[i * GSTRIDE], c) : 0u);
    }
    __syncthreads();
    for (int e = base + tid; e < end; e += 256) {
        int d = dst[e];
        int s = src[e];
        int bb = d >> SH;
        unsigned int p = atomicAdd(&cur[bb], 1u);
        if (p - (unsigned int)bb * CAPB < CAPB)
            entries[p] = (unsigned int)s | ((unsigned int)(d & (NPB - 1)) << 17);
    }
}

// ---------------- hs = bf16((x @ W1) * dinv[row]), fused degree->dinv ----------------
// block = bin b (64 rows); 256 threads; register-tiled 4x4
__global__ __launch_bounds__(256) void k_xw1(const float* __restrict__ x,
                                             const float* __restrict__ W,
                                             const unsigned int* __restrict__ gcnt,
                                             const unsigned int* __restrict__ entries,
                                             float* __restrict__ dinv,
                                             unsigned short* __restrict__ hs) {
    constexpr int XS = 68;  // 2-way bank aliasing only (free), 16B-aligned fills
    __shared__ float Ws[64 * 64];
    __shared__ float xs[64 * XS];
    __shared__ unsigned int ncnt[NPB];
    __shared__ float dinvs[NPB];
    int tid = threadIdx.x;
    int b = blockIdx.x;
    int r0 = b * 64;
    // stage W and x tile
    for (int i = tid; i < 1024; i += 256) {
        int k = i >> 4, c4 = (i & 15) << 2;
        *(float4*)&Ws[k * 64 + c4] = *(const float4*)&W[k * 64 + c4];
    }
    for (int i = tid; i < 1024; i += 256) {
        int rr = i >> 4, c4 = (i & 15) << 2;
        int r = r0 + rr;
        float4 v = make_float4(0.f, 0.f, 0.f, 0.f);
        if (r < N_NODES) v = *(const float4*)&x[(size_t)r * 64 + c4];
        *(float4*)&xs[rr * XS + c4] = v;
    }
    if (tid < NPB) ncnt[tid] = 0;
    __syncthreads();
    // per-node degree from this bin's entries
    unsigned int cntE = gcnt[b * GSTRIDE]; if (cntE > CAPB) cntE = CAPB;
    unsigned int ebase = (unsigned int)b * CAPB;
    for (unsigned int e = tid; e < cntE; e += 256)
        atomicAdd(&ncnt[(entries[ebase + e] >> 17) & (NPB - 1)], 1u);
    __syncthreads();
    if (tid < NPB) {
        int node = r0 + tid;
        float dv = rsqrtf((float)(ncnt[tid] + 1u));
        dinvs[tid] = dv;
        if (node < N_NODES) dinv[node] = dv;
    }
    __syncthreads();
    int tx = tid & 15, ty = tid >> 4;
    int c0 = tx << 2, rb = ty << 2;
    float acc[4][4] = {};
#pragma unroll 8
    for (int k = 0; k < 64; ++k) {
        float4 w = *(float4*)&Ws[k * 64 + c0];
        float x0 = xs[(rb + 0) * XS + k];
        float x1 = xs[(rb + 1) * XS + k];
        float x2 = xs[(rb + 2) * XS + k];
        float x3 = xs[(rb + 3) * XS + k];
        acc[0][0] += x0 * w.x; acc[0][1] += x0 * w.y; acc[0][2] += x0 * w.z; acc[0][3] += x0 * w.w;
        acc[1][0] += x1 * w.x; acc[1][1] += x1 * w.y; acc[1][2] += x1 * w.z; acc[1][3] += x1 * w.w;
        acc[2][0] += x2 * w.x; acc[2][1] += x2 * w.y; acc[2][2] += x2 * w.z; acc[2][3] += x2 * w.w;
        acc[3][0] += x3 * w.x; acc[3][1] += x3 * w.y; acc[3][2] += x3 * w.z; acc[3][3] += x3 * w.w;
    }
#pragma unroll
    for (int i = 0; i < 4; ++i) {
        int r = r0 + rb + i;
        if (r >= N_NODES) break;
        float dv = dinvs[rb + i];
        ushort4 p;
        p.x = f2bf(acc[i][0] * dv);
        p.y = f2bf(acc[i][1] * dv);
        p.z = f2bf(acc[i][2] * dv);
        p.w = f2bf(acc[i][3] * dv);
        *(ushort4*)&hs[(size_t)r * 64 + c0] = p;
    }
}

// ---------------- layer-1: edge-parallel gather + LDS f32 accumulate ----------------
// block = bin (64 nodes), 512 thr = 8 waves; wave handles a contiguous edge chunk,
// 2 edges per iteration (lanes 0-31 edge j, lanes 32-63 edge j+1; lane loads uint = 2 bf16)
__global__ __launch_bounds__(512) void k_agg1f(const unsigned int* __restrict__ gcnt,
                                               const unsigned int* __restrict__ entries,
                                               const unsigned short* __restrict__ hs,
                                               const float* __restrict__ dinv,
                                               unsigned short* __restrict__ out1) {
    __shared__ float acc[NPB * 64];  // 16 KB
    int tid = threadIdx.x;
    int b = blockIdx.x;
    unsigned int cntE = gcnt[b * GSTRIDE]; if (cntE > CAPB) cntE = CAPB;
    unsigned int base = (unsigned int)b * CAPB;
    // init acc = self-loop row (dinv[src] already folded into hs)
    {
        int n = tid >> 3, c8 = (tid & 7) << 3;
        int node = b * NPB + n;
        float* a = &acc[n * 64 + c8];
        if (node < N_NODES) {
            ushort4 q0 = *(const ushort4*)&hs[(size_t)node * 64 + c8];
            ushort4 q1 = *(const ushort4*)&hs[(size_t)node * 64 + c8 + 4];
            a[0] = bf2f(q0.x); a[1] = bf2f(q0.y); a[2] = bf2f(q0.z); a[3] = bf2f(q0.w);
            a[4] = bf2f(q1.x); a[5] = bf2f(q1.y); a[6] = bf2f(q1.z); a[7] = bf2f(q1.w);
        } else {
            for (int i = 0; i < 8; ++i) a[i] = 0.f;
        }
    }
    __syncthreads();
    const unsigned int* hs32 = (const unsigned int*)hs;
    int wv = tid >> 6, lane = tid & 63;
    int t = lane & 31, half = lane >> 5;
    unsigned int jb = ((cntE * (unsigned)wv) >> 3) & ~1u;
    unsigned int je = (wv == 7) ? cntE : (((cntE * (unsigned)(wv + 1)) >> 3) & ~1u);
    unsigned int j = jb;
#pragma unroll 2
    for (; j + 2 <= je; j += 2) {
        uint2 e2 = *(const uint2*)&entries[base + j];  // 8B broadcast
        unsigned int ent = half ? e2.y : e2.x;
        unsigned int s = ent & 0x1FFFFu;
        unsigned int dl = (ent >> 17) & (NPB - 1);
        unsigned int u = hs32[s * 32 + t];
        atomicAdd(&acc[dl * 64 + 2 * t],     __uint_as_float(u << 16));
        atomicAdd(&acc[dl * 64 + 2 * t + 1], __uint_as_float(u & 0xFFFF0000u));
    }
    if (j < je && half == 0) {  // odd tail: one edge, lanes 0-31 only
        unsigned int ent = entries[base + j];
        unsigned int s = ent & 0x1FFFFu;
        unsigned int dl = (ent >> 17) & (NPB - 1);
        unsigned int u = hs32[s * 32 + t];
        atomicAdd(&acc[dl * 64 + 2 * t],     __uint_as_float(u << 16));
        atomicAdd(&acc[dl * 64 + 2 * t + 1], __uint_as_float(u & 0xFFFF0000u));
    }
    __syncthreads();
    // epilogue: out1 = bf16(acc * dinv[dst])
    {
        int n = tid >> 3, c8 = (tid & 7) << 3;
        int node = b * NPB + n;
        if (node < N_NODES) {
            float dv = dinv[node];
            const float* a = &acc[n * 64 + c8];
            unsigned int w0 = (unsigned)f2bf(a[0] * dv) | ((unsigned)f2bf(a[1] * dv) << 16);
            unsigned int w1 = (unsigned)f2bf(a[2] * dv) | ((unsigned)f2bf(a[3] * dv) << 16);
            unsigned int w2 = (unsigned)f2bf(a[4] * dv) | ((unsigned)f2bf(a[5] * dv) << 16);
            unsigned int w3 = (unsigned)f2bf(a[6] * dv) | ((unsigned)f2bf(a[7] * dv) << 16);
            *(uint4*)&out1[(size_t)node * 64 + c8] = make_uint4(w0, w1, w2, w3);
        }
    }
}

// ---------------- h2s = bf16(relu(out1 + b1) @ W2 * dinv[row]) — register-tiled 2x4 ----------------
__global__ __launch_bounds__(256) void k_xw2(const unsigned short* __restrict__ out1,
                                             const float* __restrict__ b1,
                                             const float* __restrict__ W2,
                                             const float* __restrict__ dinv,
                                             unsigned short* __restrict__ h2s) {
    constexpr int RS = 66;
    __shared__ float Ws[64 * 16];
    __shared__ float rs[128 * RS];
    __shared__ float b1s[64];
    int tid = threadIdx.x;
    int r0 = blockIdx.x * 128;
    if (tid < 64) b1s[tid] = b1[tid];
    for (int i = tid; i < 256; i += 256)
        *(float4*)&Ws[i * 4] = *(const float4*)&W2[i * 4];
    __syncthreads();
    for (int i = tid; i < 2048; i += 256) {
        int rr = i >> 4, c4 = (i & 15) << 2;
        int r = r0 + rr;
        float v0 = 0.f, v1 = 0.f, v2 = 0.f, v3 = 0.f;
        if (r < N_NODES) {
            ushort4 u = *(const ushort4*)&out1[(size_t)r * 64 + c4];
            v0 = fmaxf(bf2f(u.x) + b1s[c4 + 0], 0.f);
            v1 = fmaxf(bf2f(u.y) + b1s[c4 + 1], 0.f);
            v2 = fmaxf(bf2f(u.z) + b1s[c4 + 2], 0.f);
            v3 = fmaxf(bf2f(u.w) + b1s[c4 + 3], 0.f);
        }
        float* p = &rs[rr * RS + c4];
        p[0] = v0; p[1] = v1; p[2] = v2; p[3] = v3;
    }
    __syncthreads();
    int tx = tid & 3, ty = tid >> 2;
    int c0 = tx << 2, rb = ty << 1;
    float acc[2][4] = {};
#pragma unroll 8
    for (int k = 0; k < 64; ++k) {
        float4 w = *(float4*)&Ws[k * 16 + c0];
        float x0 = rs[(rb + 0) * RS + k];
        float x1 = rs[(rb + 1) * RS + k];
        acc[0][0] += x0 * w.x; acc[0][1] += x0 * w.y; acc[0][2] += x0 * w.z; acc[0][3] += x0 * w.w;
        acc[1][0] += x1 * w.x; acc[1][1] += x1 * w.y; acc[1][2] += x1 * w.z; acc[1][3] += x1 * w.w;
    }
#pragma unroll
    for (int i = 0; i < 2; ++i) {
        int r = r0 + rb + i;
        if (r >= N_NODES) break;
        float dv = dinv[r];
        ushort4 p;
        p.x = f2bf(acc[i][0] * dv);
        p.y = f2bf(acc[i][1] * dv);
        p.z = f2bf(acc[i][2] * dv);
        p.w = f2bf(acc[i][3] * dv);
        *(ushort4*)&h2s[(size_t)r * 16 + c0] = p;
    }
}

// ---------------- layer-2: edge-parallel gather + LDS f32 accumulate ----------------
// block = bin, 512 thr; wave processes 4 edges/iter (slot=lane>>4, t=lane&15, ushort load)
__global__ __launch_bounds__(512) void k_agg2f(const unsigned int* __restrict__ gcnt,
                                               const unsigned int* __restrict__ entries,
                                               const unsigned short* __restrict__ h2s,
                                               const float* __restrict__ dinv,
                                               const float* __restrict__ b2,
                                               float* __restrict__ out) {
    __shared__ float acc[NPB * 16];  // 4 KB
    __shared__ float b2s[16];
    int tid = threadIdx.x;
    int b = blockIdx.x;
    if (tid < 16) b2s[tid] = b2[tid];
    unsigned int cntE = gcnt[b * GSTRIDE]; if (cntE > CAPB) cntE = CAPB;
    unsigned int base = (unsigned int)b * CAPB;
    // init acc = self-loop row
    if (tid < 128) {
        int n = tid >> 1, c8 = (tid & 1) << 3;
        int node = b * NPB + n;
        float* a = &acc[n * 16 + c8];
        if (node < N_NODES) {
            ushort4 q0 = *(const ushort4*)&h2s[(size_t)node * 16 + c8];
            ushort4 q1 = *(const ushort4*)&h2s[(size_t)node * 16 + c8 + 4];
            a[0] = bf2f(q0.x); a[1] = bf2f(q0.y); a[2] = bf2f(q0.z); a[3] = bf2f(q0.w);
            a[4] = bf2f(q1.x); a[5] = bf2f(q1.y); a[6] = bf2f(q1.z); a[7] = bf2f(q1.w);
        } else {
            for (int i = 0; i < 8; ++i) a[i] = 0.f;
        }
    }
    __syncthreads();
    int wv = tid >> 6, lane = tid & 63;
    int slot = lane >> 4, t = lane & 15;
    unsigned int jb = ((cntE * (unsigned)wv) >> 3) & ~3u;
    unsigned int je = (wv == 7) ? cntE : (((cntE * (unsigned)(wv + 1)) >> 3) & ~3u);
    for (unsigned int j = jb; j < je; j += 4) {
        uint4 e4 = *(const uint4*)&entries[base + j];  // 16B broadcast
        unsigned int ent = slot == 0 ? e4.x : slot == 1 ? e4.y : slot == 2 ? e4.z : e4.w;
        if (j + (unsigned)slot < je) {
            unsigned int s = ent & 0x1FFFFu;
            unsigned int dl = (ent >> 17) & (NPB - 1);
            float v = bf2f(h2s[(size_t)s * 16 + t]);
            atomicAdd(&acc[dl * 16 + t], v);
        }
    }
    __syncthreads();
    if (tid < 128) {
        int n = tid >> 1, c8 = (tid & 1) << 3;
        int node = b * NPB + n;
        if (node < N_NODES) {
            float dv = dinv[node];
            const float* a = &acc[n * 16 + c8];
            float4 o0, o1;
            o0.x = a[0] * dv + b2s[c8 + 0];
            o0.y = a[1] * dv + b2s[c8 + 1];
            o0.z = a[2] * dv + b2s[c8 + 2];
            o0.w = a[3] * dv + b2s[c8 + 3];
            o1.x = a[4] * dv + b2s[c8 + 4];
            o1.y = a[5] * dv + b2s[c8 + 5];
            o1.z = a[6] * dv + b2s[c8 + 6];
            o1.w = a[7] * dv + b2s[c8 + 7];
            *(float4*)&out[(size_t)node * 16 + c8] = o0;
            *(float4*)&out[(size_t)node * 16 + c8 + 4] = o1;
        }
    }
}

static inline size_t align256(size_t x) { return (x + 255) & ~size_t(255); }

extern "C" void kernel_launch(void* const* d_in, const int* in_sizes, int n_in,
                              void* d_out, int out_size, void* d_ws, size_t ws_size,
                              hipStream_t stream) {
    const float* x  = (const float*)d_in[0];
    const int* edge = (const int*)d_in[1];
    const float* W1 = (const float*)d_in[2];
    const float* b1 = (const float*)d_in[3];
    const float* W2 = (const float*)d_in[4];
    const float* b2 = (const float*)d_in[5];
    float* out = (float*)d_out;

    const int E = in_sizes[1] / 2;
    const int* src = edge;
    const int* dst = edge + E;

    // workspace layout (~38 MB)
    char* ws = (char*)d_ws;
    size_t o = 0;
    unsigned int* gcnt    = (unsigned int*)(ws + o); o += align256((size_t)NBINS * GSTRIDE * 4);
    float* dinv           = (float*)(ws + o);        o += align256((size_t)N_NODES * 4);
    unsigned int* entries = (unsigned int*)(ws + o); o += align256(((size_t)NBINS * CAPB + 16) * 4);
    unsigned short* hs    = (unsigned short*)(ws + o); o += align256((size_t)N_NODES * F1 * 2);
    unsigned short* out1  = (unsigned short*)(ws + o); o += align256((size_t)N_NODES * F1 * 2);
    unsigned short* h2s   = (unsigned short*)(ws + o); o += align256((size_t)N_NODES * F2 * 2);

    hipMemsetAsync(gcnt, 0, (size_t)NBINS * GSTRIDE * 4, stream);

    k_bin<<<(E + TILE - 1) / TILE, 256, 0, stream>>>(src, dst, E, gcnt, entries);

    // layer 1 (dinv fused into k_xw1)
    k_xw1<<<NBINS, 256, 0, stream>>>(x, W1, gcnt, entries, dinv, hs);
    k_agg1f<<<NBINS, 512, 0, stream>>>(gcnt, entries, hs, dinv, out1);

    // layer 2
    k_xw2<<<(N_NODES + 127) / 128, 256, 0, stream>>>(out1, b1, W2, dinv, h2s);
    k_agg2f<<<NBINS, 512, 0, stream>>>(gcnt, entries, h2s, dinv, b2, out);
}

// Round 8
// 185.395 us; speedup vs baseline: 4.4829x; 4.4829x over previous
//
#include <hip/hip_runtime.h>

constexpr int N_NODES = 100000;
constexpr int F1 = 64;   // IN_DIM == HID_DIM
constexpr int F2 = 16;   // OUT_DIM
constexpr int SH = 7;                             // bin = dst >> 7
constexpr int NPB = 128;                          // nodes per bin
constexpr int NBINS = (N_NODES + NPB - 1) / NPB;  // 782
constexpr int CAPB = 2560;                        // mean 2046, +11 sigma
constexpr int TILE = 4096;                        // edges per k_bin block

// bf16 helpers (RNE)
static __device__ __forceinline__ unsigned short f2bf(float f) {
    unsigned int u = __float_as_uint(f);
    unsigned int r = (u + 0x7fffu + ((u >> 16) & 1u)) >> 16;
    return (unsigned short)r;
}
static __device__ __forceinline__ float bf2f(unsigned short b) {
    return __uint_as_float(((unsigned int)b) << 16);
}

// ---------------- pass 1: coarse binning (block-aggregated allocation) ----------------
__global__ __launch_bounds__(256) void k_bin(const int* __restrict__ src,
                                             const int* __restrict__ dst, int E,
                                             unsigned int* __restrict__ gcnt,
                                             unsigned int* __restrict__ entries) {
    __shared__ unsigned int cnt[NBINS];
    __shared__ unsigned int cur[NBINS];
    int tid = threadIdx.x;
    int base = blockIdx.x * TILE;
    int end = min(base + TILE, E);
    for (int i = tid; i < NBINS; i += 256) cnt[i] = 0;
    __syncthreads();
    for (int e = base + tid; e < end; e += 256) atomicAdd(&cnt[dst[e] >> SH], 1u);
    __syncthreads();
    for (int i = tid; i < NBINS; i += 256) {
        unsigned int c = cnt[i];
        cur[i] = (unsigned int)i * CAPB + (c ? atomicAdd(&gcnt[i], c) : 0u);
    }
    __syncthreads();
    for (int e = base + tid; e < end; e += 256) {
        int d = dst[e];
        int s = src[e];
        int bb = d >> SH;
        unsigned int p = atomicAdd(&cur[bb], 1u);
        if (p - (unsigned int)bb * CAPB < CAPB)
            entries[p] = (unsigned int)s | ((unsigned int)(d & (NPB - 1)) << 17);
    }
}

// ---------------- CSR build ONCE: hist -> scan -> scatter to global + dinv ----------------
__global__ __launch_bounds__(256) void k_csr(const unsigned int* __restrict__ gcnt,
                                             const unsigned int* __restrict__ entries,
                                             unsigned int* __restrict__ noffg,
                                             unsigned int* __restrict__ sorted,
                                             float* __restrict__ dinv) {
    __shared__ unsigned int ncnt[NPB];
    __shared__ unsigned int noff[NPB + 1];
    __shared__ unsigned int cur[NPB];
    int tid = threadIdx.x;
    int b = blockIdx.x;
    unsigned int cntE = gcnt[b]; if (cntE > CAPB) cntE = CAPB;
    unsigned int base = (unsigned int)b * CAPB;
    if (tid < NPB) ncnt[tid] = 0;
    __syncthreads();
    for (unsigned int e = tid; e < cntE; e += 256)
        atomicAdd(&ncnt[entries[base + e] >> 17], 1u);
    __syncthreads();
    if (tid < NPB) cur[tid] = ncnt[tid];
    __syncthreads();
    for (int ofs = 1; ofs < NPB; ofs <<= 1) {
        unsigned int v = (tid < NPB && tid >= ofs) ? cur[tid - ofs] : 0u;
        __syncthreads();
        if (tid < NPB) cur[tid] += v;
        __syncthreads();
    }
    if (tid < NPB) noff[tid + 1] = cur[tid];
    if (tid == 0) noff[0] = 0;
    __syncthreads();
    if (tid < NPB) {
        int node = b * NPB + tid;
        if (node < N_NODES) dinv[node] = rsqrtf((float)(ncnt[tid] + 1u));
        cur[tid] = noff[tid];
    }
    __syncthreads();
    for (unsigned int e = tid; e < cntE; e += 256) {
        unsigned int v = entries[base + e];
        unsigned int p = atomicAdd(&cur[v >> 17], 1u);
        sorted[base + p] = v & 0x1FFFFu;
    }
    if (tid <= NPB) noffg[b * (NPB + 1) + tid] = noff[tid];
}

// ---------------- hs = bf16((x @ W1) * dinv[row]) — register-tiled 4x4 ----------------
__global__ __launch_bounds__(256) void k_xw1(const float* __restrict__ x,
                                             const float* __restrict__ W,
                                             const float* __restrict__ dinv,
                                             unsigned short* __restrict__ hs) {
    constexpr int XS = 68;
    __shared__ float Ws[64 * 64];
    __shared__ float xs[64 * XS];
    int tid = threadIdx.x;
    int r0 = blockIdx.x * 64;
    for (int i = tid; i < 1024; i += 256) {
        int k = i >> 4, c4 = (i & 15) << 2;
        *(float4*)&Ws[k * 64 + c4] = *(const float4*)&W[k * 64 + c4];
    }
    for (int i = tid; i < 1024; i += 256) {
        int rr = i >> 4, c4 = (i & 15) << 2;
        int r = r0 + rr;
        float4 v = make_float4(0.f, 0.f, 0.f, 0.f);
        if (r < N_NODES) v = *(const float4*)&x[(size_t)r * 64 + c4];
        *(float4*)&xs[rr * XS + c4] = v;
    }
    __syncthreads();
    int tx = tid & 15, ty = tid >> 4;
    int c0 = tx << 2, rb = ty << 2;
    float acc[4][4] = {};
#pragma unroll 8
    for (int k = 0; k < 64; ++k) {
        float4 w = *(float4*)&Ws[k * 64 + c0];
        float x0 = xs[(rb + 0) * XS + k];
        float x1 = xs[(rb + 1) * XS + k];
        float x2 = xs[(rb + 2) * XS + k];
        float x3 = xs[(rb + 3) * XS + k];
        acc[0][0] += x0 * w.x; acc[0][1] += x0 * w.y; acc[0][2] += x0 * w.z; acc[0][3] += x0 * w.w;
        acc[1][0] += x1 * w.x; acc[1][1] += x1 * w.y; acc[1][2] += x1 * w.z; acc[1][3] += x1 * w.w;
        acc[2][0] += x2 * w.x; acc[2][1] += x2 * w.y; acc[2][2] += x2 * w.z; acc[2][3] += x2 * w.w;
        acc[3][0] += x3 * w.x; acc[3][1] += x3 * w.y; acc[3][2] += x3 * w.z; acc[3][3] += x3 * w.w;
    }
#pragma unroll
    for (int i = 0; i < 4; ++i) {
        int r = r0 + rb + i;
        if (r >= N_NODES) break;
        float dv = dinv[r];
        ushort4 p;
        p.x = f2bf(acc[i][0] * dv);
        p.y = f2bf(acc[i][1] * dv);
        p.z = f2bf(acc[i][2] * dv);
        p.w = f2bf(acc[i][3] * dv);
        *(ushort4*)&hs[(size_t)r * 64 + c0] = p;
    }
}

// ---------------- layer-1: wave per 2 nodes (dual-chain ILP), lane = feature ----------------
__global__ __launch_bounds__(512) void k_agg1f(const unsigned int* __restrict__ noffg,
                                               const unsigned int* __restrict__ sorted,
                                               const unsigned short* __restrict__ hs,
                                               const float* __restrict__ dinv,
                                               unsigned short* __restrict__ out1) {
    __shared__ unsigned int noffs[NPB + 1];
    int tid = threadIdx.x;
    int b = blockIdx.x;
    if (tid <= NPB) noffs[tid] = noffg[b * (NPB + 1) + tid];
    __syncthreads();
    unsigned int base = (unsigned int)b * CAPB;
    int wv = tid >> 6, k = tid & 63;
    // wave handles 16 contiguous nodes: [wv*16, wv*16+16), as 8 pairs
#pragma unroll 1
    for (int p = 0; p < 8; ++p) {
        int nA = (wv << 4) + (p << 1);
        int nB = nA + 1;
        int nodeA = b * NPB + nA;
        if (nodeA >= N_NODES) break;
        int nodeB = nodeA + 1;
        bool hasB = nodeB < N_NODES;
        unsigned int jA = noffs[nA], eA = noffs[nA + 1];
        unsigned int jB = noffs[nB], eB = noffs[nB + 1];
        float accA = bf2f(hs[(size_t)nodeA * 64 + k]);  // self-loop
        float accB = hasB ? bf2f(hs[(size_t)nodeB * 64 + k]) : 0.f;
        // joint phase: 8 independent gathers in flight
        while (jA + 4 <= eA && jB + 4 <= eB) {
            unsigned int a0 = sorted[base + jA], a1 = sorted[base + jA + 1];
            unsigned int a2 = sorted[base + jA + 2], a3 = sorted[base + jA + 3];
            unsigned int b0 = sorted[base + jB], b1 = sorted[base + jB + 1];
            unsigned int b2 = sorted[base + jB + 2], b3 = sorted[base + jB + 3];
            float va0 = bf2f(hs[(size_t)a0 * 64 + k]);
            float va1 = bf2f(hs[(size_t)a1 * 64 + k]);
            float va2 = bf2f(hs[(size_t)a2 * 64 + k]);
            float va3 = bf2f(hs[(size_t)a3 * 64 + k]);
            float vb0 = bf2f(hs[(size_t)b0 * 64 + k]);
            float vb1 = bf2f(hs[(size_t)b1 * 64 + k]);
            float vb2 = bf2f(hs[(size_t)b2 * 64 + k]);
            float vb3 = bf2f(hs[(size_t)b3 * 64 + k]);
            accA += (va0 + va1) + (va2 + va3);
            accB += (vb0 + vb1) + (vb2 + vb3);
            jA += 4; jB += 4;
        }
        // drain A
        while (jA + 4 <= eA) {
            unsigned int a0 = sorted[base + jA], a1 = sorted[base + jA + 1];
            unsigned int a2 = sorted[base + jA + 2], a3 = sorted[base + jA + 3];
            float va0 = bf2f(hs[(size_t)a0 * 64 + k]);
            float va1 = bf2f(hs[(size_t)a1 * 64 + k]);
            float va2 = bf2f(hs[(size_t)a2 * 64 + k]);
            float va3 = bf2f(hs[(size_t)a3 * 64 + k]);
            accA += (va0 + va1) + (va2 + va3);
            jA += 4;
        }
        while (jA < eA) { accA += bf2f(hs[(size_t)sorted[base + jA] * 64 + k]); ++jA; }
        // drain B
        while (jB + 4 <= eB) {
            unsigned int b0 = sorted[base + jB], b1 = sorted[base + jB + 1];
            unsigned int b2 = sorted[base + jB + 2], b3 = sorted[base + jB + 3];
            float vb0 = bf2f(hs[(size_t)b0 * 64 + k]);
            float vb1 = bf2f(hs[(size_t)b1 * 64 + k]);
            float vb2 = bf2f(hs[(size_t)b2 * 64 + k]);
            float vb3 = bf2f(hs[(size_t)b3 * 64 + k]);
            accB += (vb0 + vb1) + (vb2 + vb3);
            jB += 4;
        }
        while (jB < eB) { accB += bf2f(hs[(size_t)sorted[base + jB] * 64 + k]); ++jB; }
        out1[(size_t)nodeA * 64 + k] = f2bf(accA * dinv[nodeA]);
        if (hasB) out1[(size_t)nodeB * 64 + k] = f2bf(accB * dinv[nodeB]);
    }
}

// ---------------- h2s = bf16(relu(out1 + b1) @ W2 * dinv[row]) — register-tiled 2x4 ----------------
__global__ __launch_bounds__(256) void k_xw2(const unsigned short* __restrict__ out1,
                                             const float* __restrict__ b1,
                                             const float* __restrict__ W2,
                                             const float* __restrict__ dinv,
                                             unsigned short* __restrict__ h2s) {
    constexpr int RS = 66;
    __shared__ float Ws[64 * 16];
    __shared__ float rs[128 * RS];
    __shared__ float b1s[64];
    int tid = threadIdx.x;
    int r0 = blockIdx.x * 128;
    if (tid < 64) b1s[tid] = b1[tid];
    for (int i = tid; i < 256; i += 256)
        *(float4*)&Ws[i * 4] = *(const float4*)&W2[i * 4];
    __syncthreads();
    for (int i = tid; i < 2048; i += 256) {
        int rr = i >> 4, c4 = (i & 15) << 2;
        int r = r0 + rr;
        float v0 = 0.f, v1 = 0.f, v2 = 0.f, v3 = 0.f;
        if (r < N_NODES) {
            ushort4 u = *(const ushort4*)&out1[(size_t)r * 64 + c4];
            v0 = fmaxf(bf2f(u.x) + b1s[c4 + 0], 0.f);
            v1 = fmaxf(bf2f(u.y) + b1s[c4 + 1], 0.f);
            v2 = fmaxf(bf2f(u.z) + b1s[c4 + 2], 0.f);
            v3 = fmaxf(bf2f(u.w) + b1s[c4 + 3], 0.f);
        }
        float* pp = &rs[rr * RS + c4];
        pp[0] = v0; pp[1] = v1; pp[2] = v2; pp[3] = v3;
    }
    __syncthreads();
    int tx = tid & 3, ty = tid >> 2;
    int c0 = tx << 2, rb = ty << 1;
    float acc[2][4] = {};
#pragma unroll 8
    for (int k = 0; k < 64; ++k) {
        float4 w = *(float4*)&Ws[k * 16 + c0];
        float x0 = rs[(rb + 0) * RS + k];
        float x1 = rs[(rb + 1) * RS + k];
        acc[0][0] += x0 * w.x; acc[0][1] += x0 * w.y; acc[0][2] += x0 * w.z; acc[0][3] += x0 * w.w;
        acc[1][0] += x1 * w.x; acc[1][1] += x1 * w.y; acc[1][2] += x1 * w.z; acc[1][3] += x1 * w.w;
    }
#pragma unroll
    for (int i = 0; i < 2; ++i) {
        int r = r0 + rb + i;
        if (r >= N_NODES) break;
        float dv = dinv[r];
        ushort4 p;
        p.x = f2bf(acc[i][0] * dv);
        p.y = f2bf(acc[i][1] * dv);
        p.z = f2bf(acc[i][2] * dv);
        p.w = f2bf(acc[i][3] * dv);
        *(ushort4*)&h2s[(size_t)r * 16 + c0] = p;
    }
}

// ---------------- layer-2: wave per node, 16 feats x 4 edge slots, unroll 2 ----------------
__global__ __launch_bounds__(512) void k_agg2f(const unsigned int* __restrict__ noffg,
                                               const unsigned int* __restrict__ sorted,
                                               const unsigned short* __restrict__ h2s,
                                               const float* __restrict__ dinv,
                                               const float* __restrict__ b2,
                                               float* __restrict__ out) {
    __shared__ unsigned int noffs[NPB + 1];
    __shared__ float b2s[16];
    int tid = threadIdx.x;
    int b = blockIdx.x;
    if (tid <= NPB) noffs[tid] = noffg[b * (NPB + 1) + tid];
    if (tid >= 128 && tid < 144) b2s[tid - 128] = b2[tid - 128];
    __syncthreads();
    unsigned int base = (unsigned int)b * CAPB;
    int wv = tid >> 6, lane = tid & 63;
    int k = lane & 15, slot = lane >> 4;
    // wave handles 16 contiguous nodes
    for (int p = 0; p < 16; ++p) {
        int n = (wv << 4) + p;
        int node = b * NPB + n;
        if (node >= N_NODES) break;
        unsigned int j0 = noffs[n], jend = noffs[n + 1];
        float acc = 0.f;
        for (unsigned int j = j0; j < jend; j += 8) {
            unsigned int i1 = j + (unsigned)slot;
            unsigned int i2 = i1 + 4;
            float v1 = (i1 < jend) ? bf2f(h2s[(size_t)sorted[base + i1] * 16 + k]) : 0.f;
            float v2 = (i2 < jend) ? bf2f(h2s[(size_t)sorted[base + i2] * 16 + k]) : 0.f;
            acc += v1 + v2;
        }
        acc += __shfl_xor(acc, 16);
        acc += __shfl_xor(acc, 32);
        if (lane < 16)
            out[(size_t)node * 16 + k] = (acc + bf2f(h2s[(size_t)node * 16 + k])) * dinv[node] + b2s[k];
    }
}

static inline size_t align256(size_t x) { return (x + 255) & ~size_t(255); }

extern "C" void kernel_launch(void* const* d_in, const int* in_sizes, int n_in,
                              void* d_out, int out_size, void* d_ws, size_t ws_size,
                              hipStream_t stream) {
    const float* x  = (const float*)d_in[0];
    const int* edge = (const int*)d_in[1];
    const float* W1 = (const float*)d_in[2];
    const float* b1 = (const float*)d_in[3];
    const float* W2 = (const float*)d_in[4];
    const float* b2 = (const float*)d_in[5];
    float* out = (float*)d_out;

    const int E = in_sizes[1] / 2;
    const int* src = edge;
    const int* dst = edge + E;

    // workspace layout (~50 MB)
    char* ws = (char*)d_ws;
    size_t o = 0;
    unsigned int* gcnt    = (unsigned int*)(ws + o); o += align256((size_t)NBINS * 4);
    float* dinv           = (float*)(ws + o);        o += align256((size_t)N_NODES * 4);
    unsigned int* entries = (unsigned int*)(ws + o); o += align256((size_t)NBINS * CAPB * 4);
    unsigned int* sorted  = (unsigned int*)(ws + o); o += align256((size_t)NBINS * CAPB * 4);
    unsigned int* noffg   = (unsigned int*)(ws + o); o += align256((size_t)NBINS * (NPB + 1) * 4);
    unsigned short* hs    = (unsigned short*)(ws + o); o += align256((size_t)N_NODES * F1 * 2);
    unsigned short* out1  = (unsigned short*)(ws + o); o += align256((size_t)N_NODES * F1 * 2);
    unsigned short* h2s   = (unsigned short*)(ws + o); o += align256((size_t)N_NODES * F2 * 2);

    hipMemsetAsync(gcnt, 0, (size_t)NBINS * 4, stream);

    k_bin<<<(E + TILE - 1) / TILE, 256, 0, stream>>>(src, dst, E, gcnt, entries);
    k_csr<<<NBINS, 256, 0, stream>>>(gcnt, entries, noffg, sorted, dinv);

    // layer 1
    k_xw1<<<(N_NODES + 63) / 64, 256, 0, stream>>>(x, W1, dinv, hs);
    k_agg1f<<<NBINS, 512, 0, stream>>>(noffg, sorted, hs, dinv, out1);

    // layer 2
    k_xw2<<<(N_NODES + 127) / 128, 256, 0, stream>>>(out1, b1, W2, dinv, h2s);
    k_agg2f<<<NBINS, 512, 0, stream>>>(noffg, sorted, h2s, dinv, b2, out);
}

// Round 9
// 163.806 us; speedup vs baseline: 5.0738x; 1.1318x over previous
//
#include <hip/hip_runtime.h>

constexpr int N_NODES = 100000;
constexpr int F1 = 64;   // IN_DIM == HID_DIM
constexpr int F2 = 16;   // OUT_DIM
constexpr int SH = 7;                             // bin = dst >> 7
constexpr int NPB = 128;                          // nodes per bin
constexpr int NBINS = (N_NODES + NPB - 1) / NPB;  // 782
constexpr int CAPB = 2560;                        // mean 2046, +11 sigma
constexpr int TILE = 4096;                        // edges per k_bin block

// bf16 helpers (RNE)
static __device__ __forceinline__ unsigned short f2bf(float f) {
    unsigned int u = __float_as_uint(f);
    unsigned int r = (u + 0x7fffu + ((u >> 16) & 1u)) >> 16;
    return (unsigned short)r;
}
static __device__ __forceinline__ float bf2f(unsigned short b) {
    return __uint_as_float(((unsigned int)b) << 16);
}
static __device__ __forceinline__ float lo16(unsigned int u) { return __uint_as_float(u << 16); }
static __device__ __forceinline__ float hi16(unsigned int u) { return __uint_as_float(u & 0xFFFF0000u); }

// ---------------- pass 1: coarse binning (block-aggregated allocation) ----------------
__global__ __launch_bounds__(256) void k_bin(const int* __restrict__ src,
                                             const int* __restrict__ dst, int E,
                                             unsigned int* __restrict__ gcnt,
                                             unsigned int* __restrict__ entries) {
    __shared__ unsigned int cnt[NBINS];
    __shared__ unsigned int cur[NBINS];
    int tid = threadIdx.x;
    int base = blockIdx.x * TILE;
    int end = min(base + TILE, E);
    for (int i = tid; i < NBINS; i += 256) cnt[i] = 0;
    __syncthreads();
    for (int e = base + tid; e < end; e += 256) atomicAdd(&cnt[dst[e] >> SH], 1u);
    __syncthreads();
    for (int i = tid; i < NBINS; i += 256) {
        unsigned int c = cnt[i];
        cur[i] = (unsigned int)i * CAPB + (c ? atomicAdd(&gcnt[i], c) : 0u);
    }
    __syncthreads();
    for (int e = base + tid; e < end; e += 256) {
        int d = dst[e];
        int s = src[e];
        int bb = d >> SH;
        unsigned int p = atomicAdd(&cur[bb], 1u);
        if (p - (unsigned int)bb * CAPB < CAPB)
            entries[p] = (unsigned int)s | ((unsigned int)(d & (NPB - 1)) << 17);
    }
}

// ---------------- CSR build: hist -> scan -> scatter + dinv + absolute node ranges ----------------
__global__ __launch_bounds__(256) void k_csr(const unsigned int* __restrict__ gcnt,
                                             const unsigned int* __restrict__ entries,
                                             uint2* __restrict__ nrange,
                                             unsigned int* __restrict__ sorted,
                                             float* __restrict__ dinv) {
    __shared__ unsigned int ncnt[NPB];
    __shared__ unsigned int noff[NPB + 1];
    __shared__ unsigned int cur[NPB];
    int tid = threadIdx.x;
    int b = blockIdx.x;
    unsigned int cntE = gcnt[b]; if (cntE > CAPB) cntE = CAPB;
    unsigned int base = (unsigned int)b * CAPB;
    if (tid < NPB) ncnt[tid] = 0;
    __syncthreads();
    for (unsigned int e = tid; e < cntE; e += 256)
        atomicAdd(&ncnt[entries[base + e] >> 17], 1u);
    __syncthreads();
    if (tid < NPB) cur[tid] = ncnt[tid];
    __syncthreads();
    for (int ofs = 1; ofs < NPB; ofs <<= 1) {
        unsigned int v = (tid < NPB && tid >= ofs) ? cur[tid - ofs] : 0u;
        __syncthreads();
        if (tid < NPB) cur[tid] += v;
        __syncthreads();
    }
    if (tid < NPB) noff[tid + 1] = cur[tid];
    if (tid == 0) noff[0] = 0;
    __syncthreads();
    if (tid < NPB) {
        int node = b * NPB + tid;
        if (node < N_NODES) {
            dinv[node] = rsqrtf((float)(ncnt[tid] + 1u));
            nrange[node] = make_uint2(base + noff[tid], base + noff[tid + 1]);
        }
        cur[tid] = noff[tid];
    }
    __syncthreads();
    for (unsigned int e = tid; e < cntE; e += 256) {
        unsigned int v = entries[base + e];
        unsigned int p = atomicAdd(&cur[v >> 17], 1u);
        sorted[base + p] = v & 0x1FFFFu;
    }
}

// ---------------- hs = bf16((x @ W1) * dinv[row]) — register-tiled 4x4 ----------------
__global__ __launch_bounds__(256) void k_xw1(const float* __restrict__ x,
                                             const float* __restrict__ W,
                                             const float* __restrict__ dinv,
                                             unsigned short* __restrict__ hs) {
    constexpr int XS = 68;
    __shared__ float Ws[64 * 64];
    __shared__ float xs[64 * XS];
    int tid = threadIdx.x;
    int r0 = blockIdx.x * 64;
    for (int i = tid; i < 1024; i += 256) {
        int k = i >> 4, c4 = (i & 15) << 2;
        *(float4*)&Ws[k * 64 + c4] = *(const float4*)&W[k * 64 + c4];
    }
    for (int i = tid; i < 1024; i += 256) {
        int rr = i >> 4, c4 = (i & 15) << 2;
        int r = r0 + rr;
        float4 v = make_float4(0.f, 0.f, 0.f, 0.f);
        if (r < N_NODES) v = *(const float4*)&x[(size_t)r * 64 + c4];
        *(float4*)&xs[rr * XS + c4] = v;
    }
    __syncthreads();
    int tx = tid & 15, ty = tid >> 4;
    int c0 = tx << 2, rb = ty << 2;
    float acc[4][4] = {};
#pragma unroll 8
    for (int k = 0; k < 64; ++k) {
        float4 w = *(float4*)&Ws[k * 64 + c0];
        float x0 = xs[(rb + 0) * XS + k];
        float x1 = xs[(rb + 1) * XS + k];
        float x2 = xs[(rb + 2) * XS + k];
        float x3 = xs[(rb + 3) * XS + k];
        acc[0][0] += x0 * w.x; acc[0][1] += x0 * w.y; acc[0][2] += x0 * w.z; acc[0][3] += x0 * w.w;
        acc[1][0] += x1 * w.x; acc[1][1] += x1 * w.y; acc[1][2] += x1 * w.z; acc[1][3] += x1 * w.w;
        acc[2][0] += x2 * w.x; acc[2][1] += x2 * w.y; acc[2][2] += x2 * w.z; acc[2][3] += x2 * w.w;
        acc[3][0] += x3 * w.x; acc[3][1] += x3 * w.y; acc[3][2] += x3 * w.z; acc[3][3] += x3 * w.w;
    }
#pragma unroll
    for (int i = 0; i < 4; ++i) {
        int r = r0 + rb + i;
        if (r >= N_NODES) break;
        float dv = dinv[r];
        ushort4 p;
        p.x = f2bf(acc[i][0] * dv);
        p.y = f2bf(acc[i][1] * dv);
        p.z = f2bf(acc[i][2] * dv);
        p.w = f2bf(acc[i][3] * dv);
        *(ushort4*)&hs[(size_t)r * 64 + c0] = p;
    }
}

// ---------------- layer-1: FLAT, one wave per node; 2 edges/instr (32-lane halves) ----------------
__global__ __launch_bounds__(256) void k_agg1f(const uint2* __restrict__ nrange,
                                               const unsigned int* __restrict__ sorted,
                                               const unsigned short* __restrict__ hs,
                                               const float* __restrict__ dinv,
                                               unsigned short* __restrict__ out1) {
    int gw = (blockIdx.x * 256 + threadIdx.x) >> 6;  // node
    if (gw >= N_NODES) return;
    int lane = threadIdx.x & 63;
    int half = lane >> 5, t = lane & 31;
    const unsigned int* hs32 = (const unsigned int*)hs;
    uint2 rg = nrange[gw];
    float a0 = 0.f, a1 = 0.f;  // feats 2t, 2t+1
    unsigned int j = rg.x + (unsigned)half, e = rg.y;
    // unroll 4: up to 4 gathers in flight per half
    for (; j + 6 < e; j += 8) {
        unsigned int s0 = sorted[j], s1 = sorted[j + 2], s2 = sorted[j + 4], s3 = sorted[j + 6];
        unsigned int u0 = hs32[(size_t)s0 * 32 + t];
        unsigned int u1 = hs32[(size_t)s1 * 32 + t];
        unsigned int u2 = hs32[(size_t)s2 * 32 + t];
        unsigned int u3 = hs32[(size_t)s3 * 32 + t];
        a0 += (lo16(u0) + lo16(u1)) + (lo16(u2) + lo16(u3));
        a1 += (hi16(u0) + hi16(u1)) + (hi16(u2) + hi16(u3));
    }
    for (; j < e; j += 2) {
        unsigned int u = hs32[(size_t)sorted[j] * 32 + t];
        a0 += lo16(u);
        a1 += hi16(u);
    }
    a0 += __shfl_xor(a0, 32);
    a1 += __shfl_xor(a1, 32);
    if (half == 0) {
        unsigned int u = hs32[(size_t)gw * 32 + t];  // self-loop
        a0 += lo16(u);
        a1 += hi16(u);
        float dv = dinv[gw];
        unsigned int w = (unsigned)f2bf(a0 * dv) | ((unsigned)f2bf(a1 * dv) << 16);
        ((unsigned int*)out1)[(size_t)gw * 32 + t] = w;
    }
}

// ---------------- h2s = bf16(relu(out1 + b1) @ W2 * dinv[row]) — register-tiled 2x4 ----------------
__global__ __launch_bounds__(256) void k_xw2(const unsigned short* __restrict__ out1,
                                             const float* __restrict__ b1,
                                             const float* __restrict__ W2,
                                             const float* __restrict__ dinv,
                                             unsigned short* __restrict__ h2s) {
    constexpr int RS = 66;
    __shared__ float Ws[64 * 16];
    __shared__ float rs[128 * RS];
    __shared__ float b1s[64];
    int tid = threadIdx.x;
    int r0 = blockIdx.x * 128;
    if (tid < 64) b1s[tid] = b1[tid];
    for (int i = tid; i < 256; i += 256)
        *(float4*)&Ws[i * 4] = *(const float4*)&W2[i * 4];
    __syncthreads();
    for (int i = tid; i < 2048; i += 256) {
        int rr = i >> 4, c4 = (i & 15) << 2;
        int r = r0 + rr;
        float v0 = 0.f, v1 = 0.f, v2 = 0.f, v3 = 0.f;
        if (r < N_NODES) {
            ushort4 u = *(const ushort4*)&out1[(size_t)r * 64 + c4];
            v0 = fmaxf(bf2f(u.x) + b1s[c4 + 0], 0.f);
            v1 = fmaxf(bf2f(u.y) + b1s[c4 + 1], 0.f);
            v2 = fmaxf(bf2f(u.z) + b1s[c4 + 2], 0.f);
            v3 = fmaxf(bf2f(u.w) + b1s[c4 + 3], 0.f);
        }
        float* pp = &rs[rr * RS + c4];
        pp[0] = v0; pp[1] = v1; pp[2] = v2; pp[3] = v3;
    }
    __syncthreads();
    int tx = tid & 3, ty = tid >> 2;
    int c0 = tx << 2, rb = ty << 1;
    float acc[2][4] = {};
#pragma unroll 8
    for (int k = 0; k < 64; ++k) {
        float4 w = *(float4*)&Ws[k * 16 + c0];
        float x0 = rs[(rb + 0) * RS + k];
        float x1 = rs[(rb + 1) * RS + k];
        acc[0][0] += x0 * w.x; acc[0][1] += x0 * w.y; acc[0][2] += x0 * w.z; acc[0][3] += x0 * w.w;
        acc[1][0] += x1 * w.x; acc[1][1] += x1 * w.y; acc[1][2] += x1 * w.z; acc[1][3] += x1 * w.w;
    }
#pragma unroll
    for (int i = 0; i < 2; ++i) {
        int r = r0 + rb + i;
        if (r >= N_NODES) break;
        float dv = dinv[r];
        ushort4 p;
        p.x = f2bf(acc[i][0] * dv);
        p.y = f2bf(acc[i][1] * dv);
        p.z = f2bf(acc[i][2] * dv);
        p.w = f2bf(acc[i][3] * dv);
        *(ushort4*)&h2s[(size_t)r * 16 + c0] = p;
    }
}

// ---------------- layer-2: FLAT, one wave per node; 8 edges/instr (8-lane slots) ----------------
__global__ __launch_bounds__(256) void k_agg2f(const uint2* __restrict__ nrange,
                                               const unsigned int* __restrict__ sorted,
                                               const unsigned short* __restrict__ h2s,
                                               const float* __restrict__ dinv,
                                               const float* __restrict__ b2,
                                               float* __restrict__ out) {
    int gw = (blockIdx.x * 256 + threadIdx.x) >> 6;  // node
    if (gw >= N_NODES) return;
    int lane = threadIdx.x & 63;
    int slot = lane >> 3, t = lane & 7;
    const unsigned int* h232 = (const unsigned int*)h2s;
    uint2 rg = nrange[gw];
    float a0 = 0.f, a1 = 0.f;  // feats 2t, 2t+1
    unsigned int j = rg.x, e = rg.y;
    for (; j + 16 <= e; j += 16) {
        unsigned int sA = sorted[j + slot];
        unsigned int sB = sorted[j + 8 + slot];
        unsigned int uA = h232[(size_t)sA * 8 + t];
        unsigned int uB = h232[(size_t)sB * 8 + t];
        a0 += lo16(uA) + lo16(uB);
        a1 += hi16(uA) + hi16(uB);
    }
    for (; j < e; j += 8) {
        unsigned int i1 = j + (unsigned)slot;
        if (i1 < e) {
            unsigned int u = h232[(size_t)sorted[i1] * 8 + t];
            a0 += lo16(u);
            a1 += hi16(u);
        }
    }
    a0 += __shfl_xor(a0, 8);
    a1 += __shfl_xor(a1, 8);
    a0 += __shfl_xor(a0, 16);
    a1 += __shfl_xor(a1, 16);
    a0 += __shfl_xor(a0, 32);
    a1 += __shfl_xor(a1, 32);
    if (slot == 0) {
        unsigned int u = h232[(size_t)gw * 8 + t];  // self-loop
        a0 += lo16(u);
        a1 += hi16(u);
        float dv = dinv[gw];
        float2 o;
        o.x = a0 * dv + b2[2 * t];
        o.y = a1 * dv + b2[2 * t + 1];
        *(float2*)&out[(size_t)gw * 16 + 2 * t] = o;
    }
}

static inline size_t align256(size_t x) { return (x + 255) & ~size_t(255); }

extern "C" void kernel_launch(void* const* d_in, const int* in_sizes, int n_in,
                              void* d_out, int out_size, void* d_ws, size_t ws_size,
                              hipStream_t stream) {
    const float* x  = (const float*)d_in[0];
    const int* edge = (const int*)d_in[1];
    const float* W1 = (const float*)d_in[2];
    const float* b1 = (const float*)d_in[3];
    const float* W2 = (const float*)d_in[4];
    const float* b2 = (const float*)d_in[5];
    float* out = (float*)d_out;

    const int E = in_sizes[1] / 2;
    const int* src = edge;
    const int* dst = edge + E;

    // workspace layout (~50 MB)
    char* ws = (char*)d_ws;
    size_t o = 0;
    unsigned int* gcnt    = (unsigned int*)(ws + o); o += align256((size_t)NBINS * 4);
    float* dinv           = (float*)(ws + o);        o += align256((size_t)N_NODES * 4);
    unsigned int* entries = (unsigned int*)(ws + o); o += align256((size_t)NBINS * CAPB * 4);
    unsigned int* sorted  = (unsigned int*)(ws + o); o += align256((size_t)NBINS * CAPB * 4);
    uint2* nrange         = (uint2*)(ws + o);        o += align256((size_t)N_NODES * 8);
    unsigned short* hs    = (unsigned short*)(ws + o); o += align256((size_t)N_NODES * F1 * 2);
    unsigned short* out1  = (unsigned short*)(ws + o); o += align256((size_t)N_NODES * F1 * 2);
    unsigned short* h2s   = (unsigned short*)(ws + o); o += align256((size_t)N_NODES * F2 * 2);

    hipMemsetAsync(gcnt, 0, (size_t)NBINS * 4, stream);

    k_bin<<<(E + TILE - 1) / TILE, 256, 0, stream>>>(src, dst, E, gcnt, entries);
    k_csr<<<NBINS, 256, 0, stream>>>(gcnt, entries, nrange, sorted, dinv);

    // layer 1
    k_xw1<<<(N_NODES + 63) / 64, 256, 0, stream>>>(x, W1, dinv, hs);
    {
        long long waves = (long long)N_NODES;
        int blocks = (int)((waves * 64 + 255) / 256);
        k_agg1f<<<blocks, 256, 0, stream>>>(nrange, sorted, hs, dinv, out1);
    }

    // layer 2
    k_xw2<<<(N_NODES + 127) / 128, 256, 0, stream>>>(out1, b1, W2, dinv, h2s);
    {
        long long waves = (long long)N_NODES;
        int blocks = (int)((waves * 64 + 255) / 256);
        k_agg2f<<<blocks, 256, 0, stream>>>(nrange, sorted, h2s, dinv, b2, out);
    }
}